// Round 1
// 1212.597 us; speedup vs baseline: 1.1136x; 1.1136x over previous
//
#include <hip/hip_runtime.h>
#include <hip/hip_bf16.h>

typedef __hip_bfloat16 bf16;
typedef __attribute__((ext_vector_type(8))) short short8;
typedef __attribute__((ext_vector_type(4))) float floatx4;

#define N_TOK 577
#define DIM_ 1024

__device__ __forceinline__ float bf2f(bf16 v) { return __bfloat162float(v); }
__device__ __forceinline__ bf16 f2bf(float v) { return __float2bfloat16(v); }
// fp32 -> bf16 bits, round-to-nearest-even (finite inputs)
__device__ __forceinline__ short f2bf_s(float f) {
  unsigned u = __builtin_bit_cast(unsigned, f);
  u = (u + 0x7FFFu + ((u >> 16) & 1u)) >> 16;
  return (short)u;
}

#define GLL16(g, l) __builtin_amdgcn_global_load_lds( \
    (const __attribute__((address_space(1))) void*)(g), \
    (__attribute__((address_space(3))) void*)(l), 16, 0, 0)

// Load one MFMA A/B fragment (8 consecutive k-elements) from LDS; convert if fp32.
template <typename T>
__device__ __forceinline__ short8 ldfrag(const T* base) {
  if constexpr (sizeof(T) == 2) {
    return *(const short8*)base;
  } else {
    const floatx4* p = (const floatx4*)base;
    floatx4 a = p[0], b = p[1];
    short8 o;
    o[0] = f2bf_s(a[0]); o[1] = f2bf_s(a[1]); o[2] = f2bf_s(a[2]); o[3] = f2bf_s(a[3]);
    o[4] = f2bf_s(b[0]); o[5] = f2bf_s(b[1]); o[6] = f2bf_s(b[2]); o[7] = f2bf_s(b[3]);
    return o;
  }
}

// ---------------------------------------------------------------------------
// Streaming fp32 -> bf16 conversion (RNE), 8 elems/thread/iter, grid-stride.
// ---------------------------------------------------------------------------
__global__ __launch_bounds__(256) void cvt_f32_bf16_kernel(
    const float* __restrict__ in, bf16* __restrict__ out, long n8)
{
  const long stride = (long)gridDim.x * 256;
  for (long i = (long)blockIdx.x * 256 + threadIdx.x; i < n8; i += stride) {
    const floatx4* p = (const floatx4*)in + i * 2;
    floatx4 a = p[0], b = p[1];
    short8 o;
    o[0] = f2bf_s(a[0]); o[1] = f2bf_s(a[1]); o[2] = f2bf_s(a[2]); o[3] = f2bf_s(a[3]);
    o[4] = f2bf_s(b[0]); o[5] = f2bf_s(b[1]); o[6] = f2bf_s(b[2]); o[7] = f2bf_s(b[3]);
    ((short8*)out)[i] = o;
  }
}

// ---------------------------------------------------------------------------
// GEMM: C[m,n] = sum_k A[m,k] * Bw[n,k] (+ bias[n]); fp32 accum.
// TA/TB in {float, bf16} (fp32 staged raw, converted at fragment load).
// 128x128 tile, BK=32, 256 threads (4 waves 2x2), 16x16x32 bf16 MFMA.
// ---------------------------------------------------------------------------
template <typename TA, typename TB, typename TC>
__global__ __launch_bounds__(256) void gemm_bt_kernel(
    const TA* __restrict__ A, const TB* __restrict__ Bw,
    const float* __restrict__ bias, TC* __restrict__ C,
    int M, int N, int K)
{
  __shared__ TA As[128 * 32];
  __shared__ TB Bs[128 * 32];
  const int tid = threadIdx.x;
  const int wave = tid >> 6, lane = tid & 63;
  const int r = lane & 15, q = lane >> 4;
  const int m0 = blockIdx.y * 128, n0 = blockIdx.x * 128;
  const int wm = (wave >> 1) * 64, wn = (wave & 1) * 64;

  floatx4 acc[4][4];
#pragma unroll
  for (int i = 0; i < 4; ++i)
#pragma unroll
    for (int j = 0; j < 4; ++j) acc[i][j] = (floatx4){0.f, 0.f, 0.f, 0.f};

  const TA* Ab = A + (size_t)m0 * K;
  const TB* Bb = Bw + (size_t)n0 * K;
  // staging coords: 16B per lane
  const int srowA2 = wave * 32 + (lane >> 2), skkA2 = (lane & 3) * 8;  // bf16: 8 elem
  const int srowA4 = wave * 32 + (lane >> 3), skkA4 = (lane & 7) * 4;  // fp32: 4 elem

  for (int k0 = 0; k0 < K; k0 += 32) {
    if constexpr (sizeof(TA) == 2) {
      GLL16(Ab + (size_t)srowA2 * K + k0 + skkA2, As + wave * 1024);
      GLL16(Ab + (size_t)(srowA2 + 16) * K + k0 + skkA2, As + wave * 1024 + 512);
    } else {
      GLL16(Ab + (size_t)srowA4 * K + k0 + skkA4, As + wave * 1024);
      GLL16(Ab + (size_t)(srowA4 + 8) * K + k0 + skkA4, As + wave * 1024 + 256);
      GLL16(Ab + (size_t)(srowA4 + 16) * K + k0 + skkA4, As + wave * 1024 + 512);
      GLL16(Ab + (size_t)(srowA4 + 24) * K + k0 + skkA4, As + wave * 1024 + 768);
    }
    if constexpr (sizeof(TB) == 2) {
      GLL16(Bb + (size_t)srowA2 * K + k0 + skkA2, Bs + wave * 1024);
      GLL16(Bb + (size_t)(srowA2 + 16) * K + k0 + skkA2, Bs + wave * 1024 + 512);
    } else {
      GLL16(Bb + (size_t)srowA4 * K + k0 + skkA4, Bs + wave * 1024);
      GLL16(Bb + (size_t)(srowA4 + 8) * K + k0 + skkA4, Bs + wave * 1024 + 256);
      GLL16(Bb + (size_t)(srowA4 + 16) * K + k0 + skkA4, Bs + wave * 1024 + 512);
      GLL16(Bb + (size_t)(srowA4 + 24) * K + k0 + skkA4, Bs + wave * 1024 + 768);
    }
    __syncthreads();
    short8 af[4], bfr[4];
#pragma unroll
    for (int i = 0; i < 4; ++i)
      af[i] = ldfrag(As + (wm + i * 16 + r) * 32 + q * 8);
#pragma unroll
    for (int j = 0; j < 4; ++j)
      bfr[j] = ldfrag(Bs + (wn + j * 16 + r) * 32 + q * 8);
#pragma unroll
    for (int i = 0; i < 4; ++i)
#pragma unroll
      for (int j = 0; j < 4; ++j)
        acc[i][j] = __builtin_amdgcn_mfma_f32_16x16x32_bf16(af[i], bfr[j], acc[i][j], 0, 0, 0);
    __syncthreads();
  }

#pragma unroll
  for (int j = 0; j < 4; ++j) {
    const int col = n0 + wn + j * 16 + r;
    const float bv = bias ? bias[col] : 0.f;
#pragma unroll
    for (int i = 0; i < 4; ++i) {
      size_t base = (size_t)(m0 + wm + i * 16 + q * 4) * N + col;
#pragma unroll
      for (int t = 0; t < 4; ++t) {
        float v = acc[i][j][t] + bv;
        if constexpr (sizeof(TC) == 2) C[base + (size_t)t * N] = f2bf(v);
        else                           C[base + (size_t)t * N] = v;
      }
    }
  }
}

// ---------------------------------------------------------------------------
// Adaptive pool 24x24 -> 8x8 (3x3 block mean). rep layout (b,h,64,64) bf16.
// ---------------------------------------------------------------------------
__global__ void pool_kernel(const bf16* __restrict__ w, bf16* __restrict__ repb)
{
  const int idx = blockIdx.x * 256 + threadIdx.x;
  const int d = idx & 63;
  const int p = (idx >> 6) & 63;
  const int h = (idx >> 12) & 15;
  const int b = idx >> 16;
  const int c = h * 64 + d;
  const int py = p >> 3, px = p & 7;
  const bf16* wb = w + (size_t)b * N_TOK * DIM_ + c;
  float s = 0.f;
#pragma unroll
  for (int dy = 0; dy < 3; ++dy)
#pragma unroll
    for (int dx = 0; dx < 3; ++dx) {
      int n = (py * 3 + dy) * 24 + px * 3 + dx;
      s += bf2f(wb[(size_t)n * DIM_]);
    }
  repb[idx] = f2bf(s * (1.f / 9.f));
}

// ---------------------------------------------------------------------------
// Attention 1 per (b,h): Q=rep_old(64x64), K=V=w stripe (577x64).
// Two-pass streaming softmax. Writes rep_new and per-row (m, 1/l) stats.
// ---------------------------------------------------------------------------
__global__ __launch_bounds__(256) void attn1_kernel(
    const bf16* __restrict__ w, const bf16* __restrict__ rep_old,
    bf16* __restrict__ rep_new, float* __restrict__ mst,
    float* __restrict__ lst, const float* __restrict__ step_rep)
{
  __shared__ bf16 Qs[64 * 64];
  __shared__ bf16 Ks[32 * 64];
  __shared__ bf16 Ps[4][16 * 32];

  const int tid = threadIdx.x;
  const int wave = tid >> 6, lane = tid & 63;
  const int r = lane & 15, q = lane >> 4;
  const int bh = blockIdx.x;
  const int b = bh >> 4, h = bh & 15;
  const bf16* wbase = w + (size_t)b * N_TOK * DIM_ + h * 64;

  {
    const short8* src = (const short8*)(rep_old + (size_t)bh * 4096);
    short8* dst = (short8*)Qs;
    dst[tid] = src[tid];
    dst[tid + 256] = src[tid + 256];
  }
  __syncthreads();

  short8 qf[2];
#pragma unroll
  for (int t = 0; t < 2; ++t)
    qf[t] = *(const short8*)(Qs + (wave * 16 + r) * 64 + t * 32 + q * 8);

  const float scale = 0.125f;
  float mrow[4], lrow[4];
#pragma unroll
  for (int j = 0; j < 4; ++j) { mrow[j] = -1e30f; lrow[j] = 0.f; }

  // pass 1: online (m, l)
  for (int t0 = 0; t0 < 640; t0 += 32) {
    __syncthreads();
    {
      int key = t0 + (tid >> 3);
      int ck = (tid & 7) * 8;
      int kc = key < N_TOK ? key : N_TOK - 1;
      *(short8*)(Ks + (tid >> 3) * 64 + ck) =
          *(const short8*)(wbase + (size_t)kc * DIM_ + ck);
    }
    __syncthreads();
#pragma unroll
    for (int s = 0; s < 2; ++s) {
      floatx4 sf = (floatx4){0.f, 0.f, 0.f, 0.f};
#pragma unroll
      for (int t = 0; t < 2; ++t) {
        short8 kf = *(const short8*)(Ks + (s * 16 + r) * 64 + t * 32 + q * 8);
        sf = __builtin_amdgcn_mfma_f32_16x16x32_bf16(qf[t], kf, sf, 0, 0, 0);
      }
      const int key = t0 + s * 16 + r;
      const bool valid = key < N_TOK;
#pragma unroll
      for (int j = 0; j < 4; ++j) {
        float v = valid ? sf[j] * scale : -1e30f;
        float mn = fmaxf(mrow[j], v);
        lrow[j] = lrow[j] * __expf(mrow[j] - mn) + __expf(v - mn);
        mrow[j] = mn;
      }
    }
  }
  // butterfly across the 16 lanes (same q) that share each row
#pragma unroll
  for (int off = 1; off < 16; off <<= 1) {
#pragma unroll
    for (int j = 0; j < 4; ++j) {
      float mo = __shfl_xor(mrow[j], off, 64);
      float lo = __shfl_xor(lrow[j], off, 64);
      float mn = fmaxf(mrow[j], mo);
      lrow[j] = lrow[j] * __expf(mrow[j] - mn) + lo * __expf(mo - mn);
      mrow[j] = mn;
    }
  }
  float rli[4];
#pragma unroll
  for (int j = 0; j < 4; ++j) rli[j] = 1.f / lrow[j];

  if (r == 0) {
#pragma unroll
    for (int j = 0; j < 4; ++j) {
      const int row = wave * 16 + q * 4 + j;
      mst[(size_t)bh * 64 + row] = mrow[j];
      lst[(size_t)bh * 64 + row] = rli[j];
    }
  }

  // pass 2: recompute S, P -> LDS, O = P @ V
  floatx4 oacc[4];
#pragma unroll
  for (int ds = 0; ds < 4; ++ds) oacc[ds] = (floatx4){0.f, 0.f, 0.f, 0.f};

  for (int t0 = 0; t0 < 640; t0 += 32) {
    __syncthreads();
    {
      int key = t0 + (tid >> 3);
      int ck = (tid & 7) * 8;
      int kc = key < N_TOK ? key : N_TOK - 1;
      *(short8*)(Ks + (tid >> 3) * 64 + ck) =
          *(const short8*)(wbase + (size_t)kc * DIM_ + ck);
    }
    __syncthreads();
#pragma unroll
    for (int s = 0; s < 2; ++s) {
      floatx4 sf = (floatx4){0.f, 0.f, 0.f, 0.f};
#pragma unroll
      for (int t = 0; t < 2; ++t) {
        short8 kf = *(const short8*)(Ks + (s * 16 + r) * 64 + t * 32 + q * 8);
        sf = __builtin_amdgcn_mfma_f32_16x16x32_bf16(qf[t], kf, sf, 0, 0, 0);
      }
      const int key = t0 + s * 16 + r;
      const bool valid = key < N_TOK;
#pragma unroll
      for (int j = 0; j < 4; ++j) {
        float pv = valid ? __expf(sf[j] * scale - mrow[j]) * rli[j] : 0.f;
        Ps[wave][(q * 4 + j) * 32 + s * 16 + r] = f2bf(pv);
      }
    }
    __syncthreads();
    short8 pa = *(const short8*)(Ps[wave] + r * 32 + q * 8);
#pragma unroll
    for (int ds = 0; ds < 4; ++ds) {
      short8 vf;
#pragma unroll
      for (int j = 0; j < 8; ++j)
        vf[j] = ((const short*)Ks)[(q * 8 + j) * 64 + ds * 16 + r];
      oacc[ds] = __builtin_amdgcn_mfma_f32_16x16x32_bf16(pa, vf, oacc[ds], 0, 0, 0);
    }
  }

  const float srep = step_rep[h];
#pragma unroll
  for (int ds = 0; ds < 4; ++ds)
#pragma unroll
    for (int j = 0; j < 4; ++j) {
      const int row = wave * 16 + q * 4 + j;
      const int d = ds * 16 + r;
      float old = bf2f(Qs[row * 64 + d]);
      rep_new[(size_t)bh * 4096 + row * 64 + d] = f2bf(old + srep * oacc[ds][j]);
    }
}

// ---------------------------------------------------------------------------
// Attention 2 per (b,h): Q=K=V=rep_new (64x64) -> xd2. May run IN-PLACE
// (xd2 aliases repb): whole input slice staged to LDS before any write.
// ---------------------------------------------------------------------------
__global__ __launch_bounds__(256) void attn2_kernel(
    const bf16* repb, bf16* xd2)
{
  __shared__ bf16 Rs[64 * 64];
  __shared__ bf16 RsT[64 * 64];
  __shared__ bf16 Ps2[4][16 * 64];
  const int tid = threadIdx.x;
  const int wave = tid >> 6, lane = tid & 63;
  const int r = lane & 15, q = lane >> 4;
  const int bh = blockIdx.x;
  const bf16* rb = repb + (size_t)bh * 4096;
  {
    const short8* src = (const short8*)rb;
    short8 v0 = src[tid * 2];
    short8 v1 = src[tid * 2 + 1];
    ((short8*)Rs)[tid * 2] = v0;
    ((short8*)Rs)[tid * 2 + 1] = v1;
    int row = tid >> 2;
    int dbase = (tid & 3) * 16;
#pragma unroll
    for (int i = 0; i < 8; ++i) ((short*)RsT)[(dbase + i) * 64 + row] = v0[i];
#pragma unroll
    for (int i = 0; i < 8; ++i) ((short*)RsT)[(dbase + 8 + i) * 64 + row] = v1[i];
  }
  __syncthreads();

  short8 qf[2];
#pragma unroll
  for (int t = 0; t < 2; ++t)
    qf[t] = *(const short8*)(Rs + (wave * 16 + r) * 64 + t * 32 + q * 8);

  floatx4 sacc[4];
#pragma unroll
  for (int ns = 0; ns < 4; ++ns) {
    sacc[ns] = (floatx4){0.f, 0.f, 0.f, 0.f};
#pragma unroll
    for (int t = 0; t < 2; ++t) {
      short8 kf = *(const short8*)(Rs + (ns * 16 + r) * 64 + t * 32 + q * 8);
      sacc[ns] = __builtin_amdgcn_mfma_f32_16x16x32_bf16(qf[t], kf, sacc[ns], 0, 0, 0);
    }
  }
  const float scale = 0.125f;
#pragma unroll
  for (int j = 0; j < 4; ++j) {
    float m = sacc[0][j];
#pragma unroll
    for (int ns = 1; ns < 4; ++ns) m = fmaxf(m, sacc[ns][j]);
#pragma unroll
    for (int off = 1; off < 16; off <<= 1) m = fmaxf(m, __shfl_xor(m, off, 64));
    float l = 0.f;
#pragma unroll
    for (int ns = 0; ns < 4; ++ns) {
      float e = __expf((sacc[ns][j] - m) * scale);
      sacc[ns][j] = e;
      l += e;
    }
#pragma unroll
    for (int off = 1; off < 16; off <<= 1) l += __shfl_xor(l, off, 64);
    float inv = 1.f / l;
#pragma unroll
    for (int ns = 0; ns < 4; ++ns)
      Ps2[wave][(q * 4 + j) * 64 + ns * 16 + r] = f2bf(sacc[ns][j] * inv);
  }
  __syncthreads();

  short8 pa[2];
#pragma unroll
  for (int t = 0; t < 2; ++t)
    pa[t] = *(const short8*)(Ps2[wave] + r * 64 + t * 32 + q * 8);
  bf16* ob = xd2 + (size_t)bh * 4096;
#pragma unroll
  for (int ds = 0; ds < 4; ++ds) {
    floatx4 o = (floatx4){0.f, 0.f, 0.f, 0.f};
#pragma unroll
    for (int t = 0; t < 2; ++t) {
      short8 vf = *(const short8*)(RsT + (ds * 16 + r) * 64 + t * 32 + q * 8);
      o = __builtin_amdgcn_mfma_f32_16x16x32_bf16(pa[t], vf, o, 0, 0, 0);
    }
#pragma unroll
    for (int j = 0; j < 4; ++j)
      ob[(size_t)(wave * 16 + q * 4 + j) * 64 + ds * 16 + r] = f2bf(o[j]);
  }
}

// ---------------------------------------------------------------------------
// applyattn per (b,h): recompute P tiles from (rep_old, w stripe, m, 1/l),
// out_stripe[n,d] = step_x[h] * sum_k P[k,n] * xd2[k,d]. IN-PLACE over w.
// ---------------------------------------------------------------------------
__global__ __launch_bounds__(256) void applyattn_kernel(
    bf16* wx, const bf16* __restrict__ qold, const bf16* __restrict__ xd2,
    const float* __restrict__ mst, const float* __restrict__ lst,
    const float* __restrict__ step_x)
{
  __shared__ bf16 Qold[64 * 64];
  __shared__ bf16 X2s[64 * 64];
  __shared__ bf16 Kt[64 * 64];
  __shared__ bf16 Pt[64 * 64];
  __shared__ float mlds[64], llds[64];
  const int tid = threadIdx.x;
  const int wave = tid >> 6, lane = tid & 63;
  const int r = lane & 15, q = lane >> 4;
  const int bh = blockIdx.x;
  const int b = bh >> 4, h = bh & 15;
  bf16* wbase = wx + (size_t)b * N_TOK * DIM_ + h * 64;

  {
    const short8* s1 = (const short8*)(qold + (size_t)bh * 4096);
    const short8* s2 = (const short8*)(xd2 + (size_t)bh * 4096);
    ((short8*)Qold)[tid] = s1[tid];
    ((short8*)Qold)[tid + 256] = s1[tid + 256];
    ((short8*)X2s)[tid] = s2[tid];
    ((short8*)X2s)[tid + 256] = s2[tid + 256];
    if (tid < 64) {
      mlds[tid] = mst[(size_t)bh * 64 + tid];
      llds[tid] = lst[(size_t)bh * 64 + tid];
    }
  }
  __syncthreads();

  short8 aq[4][2];
#pragma unroll
  for (int kt = 0; kt < 4; ++kt)
#pragma unroll
    for (int t = 0; t < 2; ++t)
      aq[kt][t] = *(const short8*)(Qold + (kt * 16 + r) * 64 + t * 32 + q * 8);
  short8 bx[4][2];
#pragma unroll
  for (int ds = 0; ds < 4; ++ds)
#pragma unroll
    for (int t = 0; t < 2; ++t) {
      short8 v;
#pragma unroll
      for (int j = 0; j < 8; ++j)
        v[j] = ((const short*)X2s)[(t * 32 + q * 8 + j) * 64 + ds * 16 + r];
      bx[ds][t] = v;
    }
  float mh[4][4], lh[4][4];
#pragma unroll
  for (int kt = 0; kt < 4; ++kt)
#pragma unroll
    for (int j = 0; j < 4; ++j) {
      mh[kt][j] = mlds[kt * 16 + q * 4 + j];
      lh[kt][j] = llds[kt * 16 + q * 4 + j];
    }
  const float sx = step_x[h];
  const float scale = 0.125f;

  for (int n0 = 0; n0 < N_TOK; n0 += 64) {
    __syncthreads();
    {
      int row = tid >> 2, nb = (tid & 3) * 16;
      int nrow = n0 + row;
      if (nrow > N_TOK - 1) nrow = N_TOK - 1;
      *(short8*)(Kt + row * 64 + nb) =
          *(const short8*)(wbase + (size_t)nrow * DIM_ + nb);
      *(short8*)(Kt + row * 64 + nb + 8) =
          *(const short8*)(wbase + (size_t)nrow * DIM_ + nb + 8);
    }
    __syncthreads();
    short8 kb[2];
#pragma unroll
    for (int t = 0; t < 2; ++t)
      kb[t] = *(const short8*)(Kt + (wave * 16 + r) * 64 + t * 32 + q * 8);
#pragma unroll
    for (int kt = 0; kt < 4; ++kt) {
      floatx4 sf = (floatx4){0.f, 0.f, 0.f, 0.f};
#pragma unroll
      for (int t = 0; t < 2; ++t)
        sf = __builtin_amdgcn_mfma_f32_16x16x32_bf16(aq[kt][t], kb[t], sf, 0, 0, 0);
#pragma unroll
      for (int j = 0; j < 4; ++j) {
        float p = __expf(sf[j] * scale - mh[kt][j]) * lh[kt][j];
        Pt[(kt * 16 + q * 4 + j) * 64 + wave * 16 + r] = f2bf(p);
      }
    }
    __syncthreads();
    short8 pa[2];
#pragma unroll
    for (int t = 0; t < 2; ++t) {
      short8 v;
#pragma unroll
      for (int j = 0; j < 8; ++j)
        v[j] = ((const short*)Pt)[(t * 32 + q * 8 + j) * 64 + wave * 16 + r];
      pa[t] = v;
    }
#pragma unroll
    for (int ds = 0; ds < 4; ++ds) {
      floatx4 o = (floatx4){0.f, 0.f, 0.f, 0.f};
#pragma unroll
      for (int t = 0; t < 2; ++t)
        o = __builtin_amdgcn_mfma_f32_16x16x32_bf16(pa[t], bx[ds][t], o, 0, 0, 0);
#pragma unroll
      for (int j = 0; j < 4; ++j) {
        int n = n0 + wave * 16 + q * 4 + j;
        if (n < N_TOK)
          wbase[(size_t)n * DIM_ + ds * 16 + r] = f2bf(o[j] * sx);
      }
    }
  }
}

// ---------------------------------------------------------------------------
extern "C" void kernel_launch(void* const* d_in, const int* in_sizes, int n_in,
                              void* d_out, int out_size, void* d_ws, size_t ws_size,
                              hipStream_t stream)
{
  // Reference dtypes are float32 -> all inputs/outputs are fp32.
  const float* x        = (const float*)d_in[0];
  const float* W_proj   = (const float*)d_in[1];
  const float* step_x   = (const float*)d_in[2];
  const float* step_rep = (const float*)d_in[3];
  const float* W_out    = (const float*)d_in[4];
  const float* b_out    = (const float*)d_in[5];
  float* out = (float*)d_out;

  char* ws = (char*)d_ws;
  // Layout (bf16 fast path, 306,708,480 B):
  //   wbuf   [0,            151,257,088)   w bf16, then xdelta in-place
  //   xb     [151,257,088,  302,514,176)   x in bf16 -- dead after GEMM1;
  //     repold/repnew/mst/lst ALIAS this region (first written by pool_kernel,
  //     which runs after GEMM1's last read of xb; stream-ordered => safe)
  //   repold [151,257,088, +16,777,216)
  //   repnew [168,034,304, +16,777,216)    (attn2 in-place = xd2)
  //   mst    [184,811,520, +524,288)
  //   lst    [185,335,808, +524,288)
  //   W_projb[302,514,176, +2,097,152)
  //   W_outb [304,611,328, +2,097,152)
  bf16*  wbuf   = (bf16*)ws;
  bf16*  xb     = (bf16*)(ws + 151257088ULL);
  bf16*  repold = (bf16*)(ws + 151257088ULL);
  bf16*  repnew = (bf16*)(ws + 168034304ULL);
  float* mst    = (float*)(ws + 184811520ULL);
  float* lst    = (float*)(ws + 185335808ULL);
  bf16*  wprojb = (bf16*)(ws + 302514176ULL);
  bf16*  woutb  = (bf16*)(ws + 304611328ULL);

  const size_t WS_FALLBACK = 185860096ULL;   // old fp32-staging path
  const size_t WS_BF16     = 306708480ULL;   // pre-converted bf16 path
  if (ws_size < WS_FALLBACK) return;  // diagnostic: output stays at memset(0)
  const bool use_bf16 = ws_size >= WS_BF16;

  const int M = 128 * N_TOK;  // 73856

  if (use_bf16) {
    // Pre-convert operands once (RNE, numerically identical to fragment-time cvt).
    const long n8_x = (long)M * DIM_ / 8;        // 9,453,568
    const long n8_w = (long)DIM_ * DIM_ / 8;     // 131,072
    cvt_f32_bf16_kernel<<<4096, 256, 0, stream>>>(x, xb, n8_x);
    cvt_f32_bf16_kernel<<<512, 256, 0, stream>>>(W_proj, wprojb, n8_w);
    cvt_f32_bf16_kernel<<<512, 256, 0, stream>>>(W_out, woutb, n8_w);
    gemm_bt_kernel<bf16, bf16, bf16><<<dim3(8, 577), 256, 0, stream>>>(
        xb, wprojb, nullptr, wbuf, M, DIM_, DIM_);
  } else {
    gemm_bt_kernel<float, float, bf16><<<dim3(8, 577), 256, 0, stream>>>(
        x, W_proj, nullptr, wbuf, M, DIM_, DIM_);
  }

  pool_kernel<<<32768, 256, 0, stream>>>(wbuf, repold);
  attn1_kernel<<<2048, 256, 0, stream>>>(wbuf, repold, repnew, mst, lst, step_rep);
  attn2_kernel<<<2048, 256, 0, stream>>>(repnew, repnew);  // in-place
  applyattn_kernel<<<2048, 256, 0, stream>>>(wbuf, repold, repnew, mst, lst, step_x);

  if (use_bf16) {
    gemm_bt_kernel<bf16, bf16, float><<<dim3(8, 577), 256, 0, stream>>>(
        wbuf, woutb, b_out, out, M, DIM_, DIM_);
  } else {
    gemm_bt_kernel<bf16, float, float><<<dim3(8, 577), 256, 0, stream>>>(
        wbuf, W_out, b_out, out, M, DIM_, DIM_);
  }
}